// Round 1
// baseline (1313.713 us; speedup 1.0000x reference)
//
#include <hip/hip_runtime.h>

#define N_NODES 50000
#define N_EDGES 800000
#define EPS 1e-5f

// ---------------- scatter-mean of edge_attr per dst ----------------
__global__ void k_scatter(const float4* __restrict__ ea4,
                          const int* __restrict__ ei,
                          float* __restrict__ agg,
                          float* __restrict__ cnt) {
  const int stride = gridDim.x * blockDim.x;
  const int total = N_EDGES * 16;  // 16 float4 per edge (64 floats)
  for (int t = blockIdx.x * blockDim.x + threadIdx.x; t < total; t += stride) {
    const int e = t >> 4, f4 = t & 15;
    const float4 v = ea4[t];
    const int d = ei[N_EDGES + e];          // edge_index[1][e]
    float* p = agg + (size_t)d * 64 + f4 * 4;
    atomicAdd(p + 0, v.x);
    atomicAdd(p + 1, v.y);
    atomicAdd(p + 2, v.z);
    atomicAdd(p + 3, v.w);
    if (f4 == 0) atomicAdd(cnt + d, 1.0f);
  }
}

__global__ void k_norm(float4* __restrict__ agg4, const float* __restrict__ cnt) {
  const int t = blockIdx.x * blockDim.x + threadIdx.x;
  if (t < N_NODES * 16) {
    const float inv = 1.0f / fmaxf(cnt[t >> 4], 1.0f);
    float4 v = agg4[t];
    v.x *= inv; v.y *= inv; v.z *= inv; v.w *= inv;
    agg4[t] = v;
  }
}

// ---------------- layer 0: [x|agg](128) @ W0(128x128) -> relu -> LN ----------------
__global__ void __launch_bounds__(128) k_layer0(
    const float* __restrict__ x, const float* __restrict__ agg,
    const float* __restrict__ W0, const float* __restrict__ b0,
    const float* __restrict__ g0, const float* __restrict__ be0,
    float* __restrict__ h0out) {
  __shared__ float in_lds[128];
  __shared__ float red[2][2];
  const int j = threadIdx.x;
  float w[128];
#pragma unroll
  for (int k = 0; k < 128; ++k) w[k] = W0[k * 128 + j];
  const float bj = b0[j], gj = g0[j], bej = be0[j];
  for (int n = blockIdx.x; n < N_NODES; n += gridDim.x) {
    in_lds[j] = (j < 64) ? x[(size_t)n * 64 + j] : agg[(size_t)n * 64 + (j - 64)];
    __syncthreads();
    float sum = bj;
#pragma unroll
    for (int k = 0; k < 128; ++k) sum += in_lds[k] * w[k];
    const float h = fmaxf(sum, 0.0f);
    float s1 = h, s2 = h * h;
#pragma unroll
    for (int o = 32; o; o >>= 1) { s1 += __shfl_down(s1, o); s2 += __shfl_down(s2, o); }
    const int wv = j >> 6;
    if ((j & 63) == 0) { red[wv][0] = s1; red[wv][1] = s2; }
    __syncthreads();
    const float S1 = red[0][0] + red[1][0];
    const float S2 = red[0][1] + red[1][1];
    const float m = S1 * (1.0f / 128.0f);
    const float var = S2 * (1.0f / 128.0f) - m * m;
    h0out[(size_t)n * 128 + j] = (h - m) * rsqrtf(var + EPS) * gj + bej;
  }
}

// ---------------- layer 1: [h0|agg](192) @ W1(192x64) -> relu -> LN ----------------
__global__ void __launch_bounds__(64) k_layer1(
    const float* __restrict__ h0, const float* __restrict__ agg,
    const float* __restrict__ W1, const float* __restrict__ b1,
    const float* __restrict__ g1, const float* __restrict__ be1,
    float* __restrict__ z) {
  __shared__ float in_lds[192];
  const int j = threadIdx.x;
  float w[192];
#pragma unroll
  for (int k = 0; k < 192; ++k) w[k] = W1[k * 64 + j];
  const float bj = b1[j], gj = g1[j], bej = be1[j];
  for (int n = blockIdx.x; n < N_NODES; n += gridDim.x) {
    in_lds[j] = h0[(size_t)n * 128 + j];
    in_lds[64 + j] = h0[(size_t)n * 128 + 64 + j];
    in_lds[128 + j] = agg[(size_t)n * 64 + j];
    __syncthreads();
    float sum = bj;
#pragma unroll
    for (int k = 0; k < 192; ++k) sum += in_lds[k] * w[k];
    const float h = fmaxf(sum, 0.0f);
    float s1 = h, s2 = h * h;
#pragma unroll
    for (int o = 32; o; o >>= 1) { s1 += __shfl_xor(s1, o); s2 += __shfl_xor(s2, o); }
    const float m = s1 * (1.0f / 64.0f);
    const float var = s2 * (1.0f / 64.0f) - m * m;
    z[(size_t)n * 64 + j] = (h - m) * rsqrtf(var + EPS) * gj + bej;
    __syncthreads();
  }
}

// ---------------- edge classifier: [z[src]|z[dst]](128) -> 64 relu -> 2 ----------------
__global__ void __launch_bounds__(256) k_cls(
    const float* __restrict__ z, const int* __restrict__ ei,
    const float* __restrict__ Wc0, const float* __restrict__ bc0,
    const float* __restrict__ Wc1, const float* __restrict__ bc1,
    float* __restrict__ out) {
  __shared__ float emb[4][128];
  const int lane = threadIdx.x & 63;
  const int wv = threadIdx.x >> 6;
  float w[128];
#pragma unroll
  for (int k = 0; k < 128; ++k) w[k] = Wc0[k * 64 + lane];
  const float bj = bc0[lane];
  const float w10 = Wc1[lane * 2 + 0], w11 = Wc1[lane * 2 + 1];
  const float ob0 = bc1[0], ob1 = bc1[1];
  const int estride = gridDim.x * 4;
  for (int e = blockIdx.x * 4 + wv; e < N_EDGES; e += estride) {
    const int s = ei[e], d = ei[N_EDGES + e];
    emb[wv][lane] = z[(size_t)s * 64 + lane];
    emb[wv][64 + lane] = z[(size_t)d * 64 + lane];
    float h = bj;
#pragma unroll
    for (int k = 0; k < 128; ++k) h += emb[wv][k] * w[k];
    h = fmaxf(h, 0.0f);
    float o0 = h * w10, o1 = h * w11;
#pragma unroll
    for (int o = 32; o; o >>= 1) { o0 += __shfl_xor(o0, o); o1 += __shfl_xor(o1, o); }
    if (lane == 0) {
      out[(size_t)e * 2 + 0] = o0 + ob0;
      out[(size_t)e * 2 + 1] = o1 + ob1;
    }
  }
}

extern "C" void kernel_launch(void* const* d_in, const int* in_sizes, int n_in,
                              void* d_out, int out_size, void* d_ws, size_t ws_size,
                              hipStream_t stream) {
  const float* x   = (const float*)d_in[0];
  const int*   ei  = (const int*)d_in[1];
  const float* ea  = (const float*)d_in[2];
  const float* W0  = (const float*)d_in[3];
  const float* b0  = (const float*)d_in[4];
  const float* g0  = (const float*)d_in[5];
  const float* be0 = (const float*)d_in[6];
  const float* W1  = (const float*)d_in[7];
  const float* b1  = (const float*)d_in[8];
  const float* g1  = (const float*)d_in[9];
  const float* be1 = (const float*)d_in[10];
  const float* Wc0 = (const float*)d_in[11];
  const float* bc0 = (const float*)d_in[12];
  const float* Wc1 = (const float*)d_in[13];
  const float* bc1 = (const float*)d_in[14];
  float* out = (float*)d_out;

  float* ws  = (float*)d_ws;
  float* agg = ws;                                  // N*64
  float* cnt = ws + (size_t)N_NODES * 64;           // N
  float* h0  = cnt + N_NODES;                       // N*128
  float* z   = h0 + (size_t)N_NODES * 128;          // N*64

  hipMemsetAsync(ws, 0, (size_t)(N_NODES * 65) * sizeof(float), stream);
  k_scatter<<<2048, 256, 0, stream>>>((const float4*)ea, ei, agg, cnt);
  k_norm<<<(N_NODES * 16 + 255) / 256, 256, 0, stream>>>((float4*)agg, cnt);
  k_layer0<<<1024, 128, 0, stream>>>(x, agg, W0, b0, g0, be0, h0);
  k_layer1<<<2048, 64, 0, stream>>>(h0, agg, W1, b1, g1, be1, z);
  k_cls<<<2048, 256, 0, stream>>>(z, ei, Wc0, bc0, Wc1, bc1, out);
}

// Round 2
// 851.985 us; speedup vs baseline: 1.5419x; 1.5419x over previous
//
#include <hip/hip_runtime.h>

#define N_NODES 50000
#define N_EDGES 800000
#define EPS 1e-5f

// ---------------- CSR build: count, scan, place ----------------
__global__ void k_count(const int* __restrict__ ei, int* __restrict__ cnt) {
  const int e = blockIdx.x * blockDim.x + threadIdx.x;
  if (e < N_EDGES) atomicAdd(&cnt[ei[N_EDGES + e]], 1);
}

__global__ void __launch_bounds__(1024) k_scan(const int* __restrict__ cnt,
                                               int* __restrict__ starts,
                                               int* __restrict__ pos) {
  __shared__ int part[1024];
  const int t = threadIdx.x;
  const int CH = 49;  // 1024*49 = 50176 >= 50000
  const int base = t * CH;
  int s = 0;
  for (int i = 0; i < CH; ++i) {
    const int idx = base + i;
    if (idx < N_NODES) s += cnt[idx];
  }
  part[t] = s;
  __syncthreads();
  // Hillis-Steele inclusive scan over 1024 partials
  for (int off = 1; off < 1024; off <<= 1) {
    const int v = (t >= off) ? part[t - off] : 0;
    __syncthreads();
    part[t] += v;
    __syncthreads();
  }
  int run = part[t] - s;  // exclusive prefix of this chunk
  for (int i = 0; i < CH; ++i) {
    const int idx = base + i;
    if (idx < N_NODES) {
      starts[idx] = run;
      pos[idx] = run;
      run += cnt[idx];
    }
  }
  if (t == 1023) starts[N_NODES] = run;  // == N_EDGES
}

__global__ void k_place(const int* __restrict__ ei, int* __restrict__ pos,
                        int* __restrict__ csr) {
  const int e = blockIdx.x * blockDim.x + threadIdx.x;
  if (e < N_EDGES) {
    const int d = ei[N_EDGES + e];
    const int slot = atomicAdd(&pos[d], 1);
    csr[slot] = e;
  }
}

// ---------------- gather-mean: one wave per node, lane = feature ----------------
__global__ void __launch_bounds__(256) k_gather(const float* __restrict__ ea,
                                                const int* __restrict__ csr,
                                                const int* __restrict__ starts,
                                                float* __restrict__ agg) {
  const int lane = threadIdx.x & 63;
  const int wv = threadIdx.x >> 6;
  const int wstride = gridDim.x * 4;
  for (int n = blockIdx.x * 4 + wv; n < N_NODES; n += wstride) {
    const int s0 = starts[n], s1 = starts[n + 1];
    float sum = 0.0f;
    int i = s0;
    for (; i + 1 < s1; i += 2) {
      const int e0 = csr[i], e1 = csr[i + 1];
      sum += ea[(size_t)e0 * 64 + lane] + ea[(size_t)e1 * 64 + lane];
    }
    if (i < s1) sum += ea[(size_t)csr[i] * 64 + lane];
    const int deg = s1 - s0;
    agg[(size_t)n * 64 + lane] = sum / (float)max(deg, 1);
  }
}

// ---------------- layer 0: [x|agg](128) @ W0(128x128) -> relu -> LN ----------------
__global__ void __launch_bounds__(128) k_layer0(
    const float* __restrict__ x, const float* __restrict__ agg,
    const float* __restrict__ W0, const float* __restrict__ b0,
    const float* __restrict__ g0, const float* __restrict__ be0,
    float* __restrict__ h0out) {
  __shared__ float in_lds[128];
  __shared__ float red[2][2];
  const int j = threadIdx.x;
  float w[128];
#pragma unroll
  for (int k = 0; k < 128; ++k) w[k] = W0[k * 128 + j];
  const float bj = b0[j], gj = g0[j], bej = be0[j];
  for (int n = blockIdx.x; n < N_NODES; n += gridDim.x) {
    in_lds[j] = (j < 64) ? x[(size_t)n * 64 + j] : agg[(size_t)n * 64 + (j - 64)];
    __syncthreads();
    float sum = bj;
#pragma unroll
    for (int k = 0; k < 128; ++k) sum += in_lds[k] * w[k];
    const float h = fmaxf(sum, 0.0f);
    float s1 = h, s2 = h * h;
#pragma unroll
    for (int o = 32; o; o >>= 1) { s1 += __shfl_down(s1, o); s2 += __shfl_down(s2, o); }
    const int wv = j >> 6;
    if ((j & 63) == 0) { red[wv][0] = s1; red[wv][1] = s2; }
    __syncthreads();
    const float S1 = red[0][0] + red[1][0];
    const float S2 = red[0][1] + red[1][1];
    const float m = S1 * (1.0f / 128.0f);
    const float var = S2 * (1.0f / 128.0f) - m * m;
    h0out[(size_t)n * 128 + j] = (h - m) * rsqrtf(var + EPS) * gj + bej;
  }
}

// ---------------- layer 1: [h0|agg](192) @ W1(192x64) -> relu -> LN ----------------
__global__ void __launch_bounds__(64) k_layer1(
    const float* __restrict__ h0, const float* __restrict__ agg,
    const float* __restrict__ W1, const float* __restrict__ b1,
    const float* __restrict__ g1, const float* __restrict__ be1,
    float* __restrict__ z) {
  __shared__ float in_lds[192];
  const int j = threadIdx.x;
  float w[192];
#pragma unroll
  for (int k = 0; k < 192; ++k) w[k] = W1[k * 64 + j];
  const float bj = b1[j], gj = g1[j], bej = be1[j];
  for (int n = blockIdx.x; n < N_NODES; n += gridDim.x) {
    in_lds[j] = h0[(size_t)n * 128 + j];
    in_lds[64 + j] = h0[(size_t)n * 128 + 64 + j];
    in_lds[128 + j] = agg[(size_t)n * 64 + j];
    __syncthreads();
    float sum = bj;
#pragma unroll
    for (int k = 0; k < 192; ++k) sum += in_lds[k] * w[k];
    const float h = fmaxf(sum, 0.0f);
    float s1 = h, s2 = h * h;
#pragma unroll
    for (int o = 32; o; o >>= 1) { s1 += __shfl_xor(s1, o); s2 += __shfl_xor(s2, o); }
    const float m = s1 * (1.0f / 64.0f);
    const float var = s2 * (1.0f / 64.0f) - m * m;
    z[(size_t)n * 64 + j] = (h - m) * rsqrtf(var + EPS) * gj + bej;
    __syncthreads();
  }
}

// ---------------- edge classifier: [z[src]|z[dst]](128) -> 64 relu -> 2 ----------------
__global__ void __launch_bounds__(256) k_cls(
    const float* __restrict__ z, const int* __restrict__ ei,
    const float* __restrict__ Wc0, const float* __restrict__ bc0,
    const float* __restrict__ Wc1, const float* __restrict__ bc1,
    float* __restrict__ out) {
  __shared__ float emb[4][128];
  const int lane = threadIdx.x & 63;
  const int wv = threadIdx.x >> 6;
  float w[128];
#pragma unroll
  for (int k = 0; k < 128; ++k) w[k] = Wc0[k * 64 + lane];
  const float bj = bc0[lane];
  const float w10 = Wc1[lane * 2 + 0], w11 = Wc1[lane * 2 + 1];
  const float ob0 = bc1[0], ob1 = bc1[1];
  const int estride = gridDim.x * 4;
  for (int e = blockIdx.x * 4 + wv; e < N_EDGES; e += estride) {
    const int s = ei[e], d = ei[N_EDGES + e];
    emb[wv][lane] = z[(size_t)s * 64 + lane];
    emb[wv][64 + lane] = z[(size_t)d * 64 + lane];
    float h = bj;
#pragma unroll
    for (int k = 0; k < 128; ++k) h += emb[wv][k] * w[k];
    h = fmaxf(h, 0.0f);
    float o0 = h * w10, o1 = h * w11;
#pragma unroll
    for (int o = 32; o; o >>= 1) { o0 += __shfl_xor(o0, o); o1 += __shfl_xor(o1, o); }
    if (lane == 0) {
      out[(size_t)e * 2 + 0] = o0 + ob0;
      out[(size_t)e * 2 + 1] = o1 + ob1;
    }
  }
}

extern "C" void kernel_launch(void* const* d_in, const int* in_sizes, int n_in,
                              void* d_out, int out_size, void* d_ws, size_t ws_size,
                              hipStream_t stream) {
  const float* x   = (const float*)d_in[0];
  const int*   ei  = (const int*)d_in[1];
  const float* ea  = (const float*)d_in[2];
  const float* W0  = (const float*)d_in[3];
  const float* b0  = (const float*)d_in[4];
  const float* g0  = (const float*)d_in[5];
  const float* be0 = (const float*)d_in[6];
  const float* W1  = (const float*)d_in[7];
  const float* b1  = (const float*)d_in[8];
  const float* g1  = (const float*)d_in[9];
  const float* be1 = (const float*)d_in[10];
  const float* Wc0 = (const float*)d_in[11];
  const float* bc0 = (const float*)d_in[12];
  const float* Wc1 = (const float*)d_in[13];
  const float* bc1 = (const float*)d_in[14];
  float* out = (float*)d_out;

  float* ws  = (float*)d_ws;
  float* agg = ws;                                   // N*64 floats
  float* h0  = agg + (size_t)N_NODES * 64;           // N*128 floats (csr aliases)
  float* z   = h0 + (size_t)N_NODES * 128;           // N*64 floats
  int* cnt    = (int*)(z + (size_t)N_NODES * 64);    // N
  int* starts = cnt + N_NODES;                       // N+1
  int* pos    = starts + N_NODES + 1;                // N
  int* csr    = (int*)h0;                            // E ints, dead before h0 written

  hipMemsetAsync(cnt, 0, N_NODES * sizeof(int), stream);
  k_count<<<(N_EDGES + 255) / 256, 256, 0, stream>>>(ei, cnt);
  k_scan<<<1, 1024, 0, stream>>>(cnt, starts, pos);
  k_place<<<(N_EDGES + 255) / 256, 256, 0, stream>>>(ei, pos, csr);
  k_gather<<<12500, 256, 0, stream>>>(ea, csr, starts, agg);
  k_layer0<<<1024, 128, 0, stream>>>(x, agg, W0, b0, g0, be0, h0);
  k_layer1<<<2048, 64, 0, stream>>>(h0, agg, W1, b1, g1, be1, z);
  k_cls<<<2048, 256, 0, stream>>>(z, ei, Wc0, bc0, Wc1, bc1, out);
}

// Round 3
// 462.429 us; speedup vs baseline: 2.8409x; 1.8424x over previous
//
#include <hip/hip_runtime.h>
#include <hip/hip_bf16.h>

#define N_NODES 50000
#define N_EDGES 800000
#define EPS 1e-5f

typedef __attribute__((ext_vector_type(8))) short short8;
typedef __attribute__((ext_vector_type(4))) float f32x4;

static __device__ __forceinline__ unsigned short f2bf(float f) {
  union { float f; unsigned u; } v; v.f = f;
  const unsigned r = v.u + 0x7FFF + ((v.u >> 16) & 1);  // round-to-nearest-even
  return (unsigned short)(r >> 16);
}

// ---------------- CSR build: count, scan, place ----------------
__global__ void k_count(const int* __restrict__ ei, int* __restrict__ cnt) {
  const int e = blockIdx.x * blockDim.x + threadIdx.x;
  if (e < N_EDGES) atomicAdd(&cnt[ei[N_EDGES + e]], 1);
}

__global__ void __launch_bounds__(1024) k_scan(const int* __restrict__ cnt,
                                               int* __restrict__ starts,
                                               int* __restrict__ pos) {
  __shared__ int part[1024];
  const int t = threadIdx.x;
  const int CH = 49;  // 1024*49 = 50176 >= 50000
  const int base = t * CH;
  int s = 0;
  for (int i = 0; i < CH; ++i) {
    const int idx = base + i;
    if (idx < N_NODES) s += cnt[idx];
  }
  part[t] = s;
  __syncthreads();
  for (int off = 1; off < 1024; off <<= 1) {
    const int v = (t >= off) ? part[t - off] : 0;
    __syncthreads();
    part[t] += v;
    __syncthreads();
  }
  int run = part[t] - s;
  for (int i = 0; i < CH; ++i) {
    const int idx = base + i;
    if (idx < N_NODES) {
      starts[idx] = run;
      pos[idx] = run;
      run += cnt[idx];
    }
  }
  if (t == 1023) starts[N_NODES] = run;
}

__global__ void k_place(const int* __restrict__ ei, int* __restrict__ pos,
                        int* __restrict__ csr) {
  const int e = blockIdx.x * blockDim.x + threadIdx.x;
  if (e < N_EDGES) {
    const int d = ei[N_EDGES + e];
    const int slot = atomicAdd(&pos[d], 1);
    csr[slot] = e;
  }
}

// ---------------- gather-mean: one wave per node, lane = feature ----------------
__global__ void __launch_bounds__(256) k_gather(const float* __restrict__ ea,
                                                const int* __restrict__ csr,
                                                const int* __restrict__ starts,
                                                float* __restrict__ agg) {
  const int lane = threadIdx.x & 63;
  const int wv = threadIdx.x >> 6;
  const int wstride = gridDim.x * 4;
  for (int n = blockIdx.x * 4 + wv; n < N_NODES; n += wstride) {
    const int s0 = starts[n], s1 = starts[n + 1];
    float sum = 0.0f;
    int i = s0;
    for (; i + 1 < s1; i += 2) {
      const int e0 = csr[i], e1 = csr[i + 1];
      sum += ea[(size_t)e0 * 64 + lane] + ea[(size_t)e1 * 64 + lane];
    }
    if (i < s1) sum += ea[(size_t)csr[i] * 64 + lane];
    const int deg = s1 - s0;
    agg[(size_t)n * 64 + lane] = sum / (float)max(deg, 1);
  }
}

// ---------------- layer 0: [x|agg](128) @ W0(128x128) -> relu -> LN ----------------
__global__ void __launch_bounds__(128) k_layer0(
    const float* __restrict__ x, const float* __restrict__ agg,
    const float* __restrict__ W0, const float* __restrict__ b0,
    const float* __restrict__ g0, const float* __restrict__ be0,
    float* __restrict__ h0out) {
  __shared__ float in_lds[128];
  __shared__ float red[2][2];
  const int j = threadIdx.x;
  float w[128];
#pragma unroll
  for (int k = 0; k < 128; ++k) w[k] = W0[k * 128 + j];
  const float bj = b0[j], gj = g0[j], bej = be0[j];
  for (int n = blockIdx.x; n < N_NODES; n += gridDim.x) {
    in_lds[j] = (j < 64) ? x[(size_t)n * 64 + j] : agg[(size_t)n * 64 + (j - 64)];
    __syncthreads();
    float sum = bj;
#pragma unroll
    for (int k = 0; k < 128; ++k) sum += in_lds[k] * w[k];
    const float h = fmaxf(sum, 0.0f);
    float s1 = h, s2 = h * h;
#pragma unroll
    for (int o = 32; o; o >>= 1) { s1 += __shfl_down(s1, o); s2 += __shfl_down(s2, o); }
    const int wv = j >> 6;
    if ((j & 63) == 0) { red[wv][0] = s1; red[wv][1] = s2; }
    __syncthreads();
    const float S1 = red[0][0] + red[1][0];
    const float S2 = red[0][1] + red[1][1];
    const float m = S1 * (1.0f / 128.0f);
    const float var = S2 * (1.0f / 128.0f) - m * m;
    h0out[(size_t)n * 128 + j] = (h - m) * rsqrtf(var + EPS) * gj + bej;
  }
}

// ---------------- layer 1: [h0|agg](192) @ W1(192x64) -> relu -> LN -> bf16 z ----------------
__global__ void __launch_bounds__(64) k_layer1(
    const float* __restrict__ h0, const float* __restrict__ agg,
    const float* __restrict__ W1, const float* __restrict__ b1,
    const float* __restrict__ g1, const float* __restrict__ be1,
    unsigned short* __restrict__ zb) {
  __shared__ float in_lds[192];
  const int j = threadIdx.x;
  float w[192];
#pragma unroll
  for (int k = 0; k < 192; ++k) w[k] = W1[k * 64 + j];
  const float bj = b1[j], gj = g1[j], bej = be1[j];
  for (int n = blockIdx.x; n < N_NODES; n += gridDim.x) {
    in_lds[j] = h0[(size_t)n * 128 + j];
    in_lds[64 + j] = h0[(size_t)n * 128 + 64 + j];
    in_lds[128 + j] = agg[(size_t)n * 64 + j];
    __syncthreads();
    float sum = bj;
#pragma unroll
    for (int k = 0; k < 192; ++k) sum += in_lds[k] * w[k];
    const float h = fmaxf(sum, 0.0f);
    float s1 = h, s2 = h * h;
#pragma unroll
    for (int o = 32; o; o >>= 1) { s1 += __shfl_xor(s1, o); s2 += __shfl_xor(s2, o); }
    const float m = s1 * (1.0f / 64.0f);
    const float var = s2 * (1.0f / 64.0f) - m * m;
    zb[(size_t)n * 64 + j] = f2bf((h - m) * rsqrtf(var + EPS) * gj + bej);
    __syncthreads();
  }
}

// ---------------- edge classifier via MFMA ----------------
// out[e] = relu([z[src]|z[dst]] @ Wc0 + bc0) @ Wc1 + bc1
// tile = 64 edges/block; A-tile [64][128] bf16 in LDS (XOR-swizzled);
// Wc0 as 16 register B-frags; 16x16x32 bf16 MFMA; fused epilogue.
__global__ void __launch_bounds__(256) k_cls_mfma(
    const unsigned short* __restrict__ zb, const int* __restrict__ ei,
    const float* __restrict__ Wc0, const float* __restrict__ bc0,
    const float* __restrict__ Wc1, const float* __restrict__ bc1,
    float* __restrict__ out) {
  __shared__ unsigned short atile[64 * 128];  // 16 KB
  const int t = threadIdx.x;
  const int lane = t & 63;
  const int w = t >> 6;     // wave 0..3 -> edge rows [w*16, w*16+16)
  const int m = lane & 15;
  const int g = lane >> 4;  // 0..3

  // B-frags: B[k][n], lane holds k = ks*32 + 8*g + j, n = nt*16 + m
  short8 bfrag[4][4];
#pragma unroll
  for (int ks = 0; ks < 4; ++ks)
#pragma unroll
    for (int nt = 0; nt < 4; ++nt) {
      short8 f;
#pragma unroll
      for (int j = 0; j < 8; ++j)
        f[j] = (short)f2bf(Wc0[(ks * 32 + 8 * g + j) * 64 + nt * 16 + m]);
      bfrag[ks][nt] = f;
    }
  float wc1v0[4], wc1v1[4], bc0v[4];
#pragma unroll
  for (int nt = 0; nt < 4; ++nt) {
    const int j = nt * 16 + m;
    wc1v0[nt] = Wc1[j * 2 + 0];
    wc1v1[nt] = Wc1[j * 2 + 1];
    bc0v[nt] = bc0[j];
  }
  const float ob0 = bc1[0], ob1 = bc1[1];

  for (int tile = blockIdx.x; tile < N_EDGES / 64; tile += gridDim.x) {
    const int ebase = tile * 64;
    // stage: 128 half-rows of 128B each; 8 lanes x 16B per half-row
#pragma unroll
    for (int ro = 0; ro < 4; ++ro) {
      const int hr = ro * 32 + (t >> 3);
      const int el = hr >> 1, half = hr & 1;
      const int e = ebase + el;
      const int node = half ? ei[N_EDGES + e] : ei[e];
      const uint4 v = *(const uint4*)(zb + (size_t)node * 64 + (t & 7) * 8);
      const int col = (half * 128 + (t & 7) * 16) ^ ((el & 7) << 4);
      *(uint4*)((char*)atile + el * 256 + col) = v;
    }
    __syncthreads();

    f32x4 acc0 = {0.f, 0.f, 0.f, 0.f}, acc1 = acc0, acc2 = acc0, acc3 = acc0;
#pragma unroll
    for (int ks = 0; ks < 4; ++ks) {
      const int row = w * 16 + m;
      const int col = (ks * 64 + g * 16) ^ ((row & 7) << 4);
      const short8 a = *(const short8*)((const char*)atile + row * 256 + col);
      acc0 = __builtin_amdgcn_mfma_f32_16x16x32_bf16(a, bfrag[ks][0], acc0, 0, 0, 0);
      acc1 = __builtin_amdgcn_mfma_f32_16x16x32_bf16(a, bfrag[ks][1], acc1, 0, 0, 0);
      acc2 = __builtin_amdgcn_mfma_f32_16x16x32_bf16(a, bfrag[ks][2], acc2, 0, 0, 0);
      acc3 = __builtin_amdgcn_mfma_f32_16x16x32_bf16(a, bfrag[ks][3], acc3, 0, 0, 0);
    }
    // epilogue: h = relu(C + bc0); p = h @ Wc1 partials; reduce over 16-lane group
    float p0[4], p1[4];
#pragma unroll
    for (int r = 0; r < 4; ++r) { p0[r] = 0.f; p1[r] = 0.f; }
#pragma unroll
    for (int r = 0; r < 4; ++r) {
      const float h0v = fmaxf(acc0[r] + bc0v[0], 0.f);
      const float h1v = fmaxf(acc1[r] + bc0v[1], 0.f);
      const float h2v = fmaxf(acc2[r] + bc0v[2], 0.f);
      const float h3v = fmaxf(acc3[r] + bc0v[3], 0.f);
      p0[r] = h0v * wc1v0[0] + h1v * wc1v0[1] + h2v * wc1v0[2] + h3v * wc1v0[3];
      p1[r] = h0v * wc1v1[0] + h1v * wc1v1[1] + h2v * wc1v1[2] + h3v * wc1v1[3];
    }
#pragma unroll
    for (int mask = 1; mask <= 8; mask <<= 1)
#pragma unroll
      for (int r = 0; r < 4; ++r) {
        p0[r] += __shfl_xor(p0[r], mask);
        p1[r] += __shfl_xor(p1[r], mask);
      }
    // lane m in [0,8): writes edge (ebase + w*16 + g*4 + (m>>1)), out channel m&1
    const int eout = ebase + w * 16 + g * 4;
#pragma unroll
    for (int r = 0; r < 4; ++r) {
      if (m == 2 * r) out[(size_t)(eout + r) * 2 + 0] = p0[r] + ob0;
      if (m == 2 * r + 1) out[(size_t)(eout + r) * 2 + 1] = p1[r] + ob1;
    }
    __syncthreads();
  }
}

extern "C" void kernel_launch(void* const* d_in, const int* in_sizes, int n_in,
                              void* d_out, int out_size, void* d_ws, size_t ws_size,
                              hipStream_t stream) {
  const float* x   = (const float*)d_in[0];
  const int*   ei  = (const int*)d_in[1];
  const float* ea  = (const float*)d_in[2];
  const float* W0  = (const float*)d_in[3];
  const float* b0  = (const float*)d_in[4];
  const float* g0  = (const float*)d_in[5];
  const float* be0 = (const float*)d_in[6];
  const float* W1  = (const float*)d_in[7];
  const float* b1  = (const float*)d_in[8];
  const float* g1  = (const float*)d_in[9];
  const float* be1 = (const float*)d_in[10];
  const float* Wc0 = (const float*)d_in[11];
  const float* bc0 = (const float*)d_in[12];
  const float* Wc1 = (const float*)d_in[13];
  const float* bc1 = (const float*)d_in[14];
  float* out = (float*)d_out;

  float* ws  = (float*)d_ws;
  float* agg = ws;                                     // N*64 f32
  float* h0  = agg + (size_t)N_NODES * 64;             // N*128 f32 (csr aliases)
  unsigned short* zb = (unsigned short*)(h0 + (size_t)N_NODES * 128);  // N*64 bf16
  int* cnt    = (int*)(zb + (size_t)N_NODES * 64);     // N
  int* starts = cnt + N_NODES;                         // N+1
  int* pos    = starts + N_NODES + 1;                  // N
  int* csr    = (int*)h0;                              // E ints, dead before h0 written

  hipMemsetAsync(cnt, 0, N_NODES * sizeof(int), stream);
  k_count<<<(N_EDGES + 255) / 256, 256, 0, stream>>>(ei, cnt);
  k_scan<<<1, 1024, 0, stream>>>(cnt, starts, pos);
  k_place<<<(N_EDGES + 255) / 256, 256, 0, stream>>>(ei, pos, csr);
  k_gather<<<12500, 256, 0, stream>>>(ea, csr, starts, agg);
  k_layer0<<<1024, 128, 0, stream>>>(x, agg, W0, b0, g0, be0, h0);
  k_layer1<<<2048, 64, 0, stream>>>(h0, agg, W1, b1, g1, be1, zb);
  k_cls_mfma<<<2048, 256, 0, stream>>>(zb, ei, Wc0, bc0, Wc1, bc1, out);
}

// Round 4
// 354.265 us; speedup vs baseline: 3.7083x; 1.3053x over previous
//
#include <hip/hip_runtime.h>
#include <hip/hip_bf16.h>

#define N_NODES 50000
#define N_EDGES 800000
#define EPS 1e-5f
#define SCAN_BLOCKS 49  // 49 * 1024 = 50176 >= N_NODES

typedef __attribute__((ext_vector_type(8))) short short8;
typedef __attribute__((ext_vector_type(4))) float f32x4;

static __device__ __forceinline__ unsigned short f2bf(float f) {
  union { float f; unsigned u; } v; v.f = f;
  const unsigned r = v.u + 0x7FFF + ((v.u >> 16) & 1);  // round-to-nearest-even
  return (unsigned short)(r >> 16);
}

// ---------------- CSR build: count, scan(3-phase), place ----------------
__global__ void k_count(const int* __restrict__ ei, int* __restrict__ cnt) {
  const int e = blockIdx.x * blockDim.x + threadIdx.x;
  if (e < N_EDGES) atomicAdd(&cnt[ei[N_EDGES + e]], 1);
}

// phase 1: per-block exclusive scan of 1024 counts (4/thread), block sums out
__global__ void __launch_bounds__(256) k_scan_blk(const int* __restrict__ cnt,
                                                  int* __restrict__ starts,
                                                  int* __restrict__ bsum) {
  __shared__ int lds[256];
  const int t = threadIdx.x, b = blockIdx.x;
  const int base = b * 1024 + t * 4;
  int c0 = 0, c1 = 0, c2 = 0, c3 = 0;
  if (base + 3 < N_NODES) {
    const int4 c = *(const int4*)(cnt + base);
    c0 = c.x; c1 = c.y; c2 = c.z; c3 = c.w;
  } else {
    if (base + 0 < N_NODES) c0 = cnt[base + 0];
    if (base + 1 < N_NODES) c1 = cnt[base + 1];
    if (base + 2 < N_NODES) c2 = cnt[base + 2];
    if (base + 3 < N_NODES) c3 = cnt[base + 3];
  }
  const int s = c0 + c1 + c2 + c3;
  lds[t] = s;
  __syncthreads();
  for (int off = 1; off < 256; off <<= 1) {
    const int v = (t >= off) ? lds[t - off] : 0;
    __syncthreads();
    lds[t] += v;
    __syncthreads();
  }
  int run = lds[t] - s;  // exclusive prefix within block
  if (t == 255) bsum[b] = lds[255];
  const int o0 = run; run += c0;
  const int o1 = run; run += c1;
  const int o2 = run; run += c2;
  const int o3 = run;
  if (base + 3 < N_NODES) {
    *(int4*)(starts + base) = make_int4(o0, o1, o2, o3);
  } else {
    if (base + 0 < N_NODES) starts[base + 0] = o0;
    if (base + 1 < N_NODES) starts[base + 1] = o1;
    if (base + 2 < N_NODES) starts[base + 2] = o2;
    if (base + 3 < N_NODES) starts[base + 3] = o3;
  }
}

// phase 2: exclusive scan of the 49 block sums (one wave)
__global__ void __launch_bounds__(64) k_scan_top(int* __restrict__ bsum) {
  const int t = threadIdx.x;
  int v = (t < SCAN_BLOCKS) ? bsum[t] : 0;
  const int orig = v;
  for (int off = 1; off < 64; off <<= 1) {
    const int u = __shfl_up(v, off);
    if (t >= off) v += u;
  }
  if (t < SCAN_BLOCKS) bsum[t] = v - orig;  // exclusive
}

// phase 3: add block offset; write starts & pos; starts[N] = E
__global__ void __launch_bounds__(256) k_scan_add(int* __restrict__ starts,
                                                  int* __restrict__ pos,
                                                  const int* __restrict__ bsum) {
  const int t = threadIdx.x, b = blockIdx.x;
  const int off = bsum[b];
  const int base = b * 1024 + t * 4;
  if (base + 3 < N_NODES) {
    int4 v = *(const int4*)(starts + base);
    v.x += off; v.y += off; v.z += off; v.w += off;
    *(int4*)(starts + base) = v;
    *(int4*)(pos + base) = v;
  } else {
    for (int i = 0; i < 4; ++i)
      if (base + i < N_NODES) {
        const int v = starts[base + i] + off;
        starts[base + i] = v;
        pos[base + i] = v;
      }
  }
  if (b == 0 && t == 0) starts[N_NODES] = N_EDGES;
}

__global__ void k_place(const int* __restrict__ ei, int* __restrict__ pos,
                        int* __restrict__ csr) {
  const int e = blockIdx.x * blockDim.x + threadIdx.x;
  if (e < N_EDGES) {
    const int d = ei[N_EDGES + e];
    const int slot = atomicAdd(&pos[d], 1);
    csr[slot] = e;
  }
}

// ---------------- gather-mean: one wave per node, lane = feature ----------------
__global__ void __launch_bounds__(256) k_gather(const float* __restrict__ ea,
                                                const int* __restrict__ csr,
                                                const int* __restrict__ starts,
                                                float* __restrict__ agg) {
  const int lane = threadIdx.x & 63;
  const int wv = threadIdx.x >> 6;
  const int wstride = gridDim.x * 4;
  for (int n = blockIdx.x * 4 + wv; n < N_NODES; n += wstride) {
    const int s0 = starts[n], s1 = starts[n + 1];
    float sum = 0.0f;
    int i = s0;
    for (; i + 1 < s1; i += 2) {
      const int e0 = csr[i], e1 = csr[i + 1];
      sum += ea[(size_t)e0 * 64 + lane] + ea[(size_t)e1 * 64 + lane];
    }
    if (i < s1) sum += ea[(size_t)csr[i] * 64 + lane];
    const int deg = s1 - s0;
    agg[(size_t)n * 64 + lane] = sum / (float)max(deg, 1);
  }
}

// ---------------- layer 0: [x|agg](128) @ W0(128x128) -> relu -> LN ----------------
__global__ void __launch_bounds__(128) k_layer0(
    const float* __restrict__ x, const float* __restrict__ agg,
    const float* __restrict__ W0, const float* __restrict__ b0,
    const float* __restrict__ g0, const float* __restrict__ be0,
    float* __restrict__ h0out) {
  __shared__ float in_lds[128];
  __shared__ float red[2][2];
  const int j = threadIdx.x;
  float w[128];
#pragma unroll
  for (int k = 0; k < 128; ++k) w[k] = W0[k * 128 + j];
  const float bj = b0[j], gj = g0[j], bej = be0[j];
  for (int n = blockIdx.x; n < N_NODES; n += gridDim.x) {
    in_lds[j] = (j < 64) ? x[(size_t)n * 64 + j] : agg[(size_t)n * 64 + (j - 64)];
    __syncthreads();
    float sum = bj;
#pragma unroll
    for (int k = 0; k < 128; ++k) sum += in_lds[k] * w[k];
    const float h = fmaxf(sum, 0.0f);
    float s1 = h, s2 = h * h;
#pragma unroll
    for (int o = 32; o; o >>= 1) { s1 += __shfl_down(s1, o); s2 += __shfl_down(s2, o); }
    const int wv = j >> 6;
    if ((j & 63) == 0) { red[wv][0] = s1; red[wv][1] = s2; }
    __syncthreads();
    const float S1 = red[0][0] + red[1][0];
    const float S2 = red[0][1] + red[1][1];
    const float m = S1 * (1.0f / 128.0f);
    const float var = S2 * (1.0f / 128.0f) - m * m;
    h0out[(size_t)n * 128 + j] = (h - m) * rsqrtf(var + EPS) * gj + bej;
  }
}

// ---------------- layer 1: [h0|agg](192) @ W1(192x64) -> relu -> LN -> bf16 z ----------------
__global__ void __launch_bounds__(64) k_layer1(
    const float* __restrict__ h0, const float* __restrict__ agg,
    const float* __restrict__ W1, const float* __restrict__ b1,
    const float* __restrict__ g1, const float* __restrict__ be1,
    unsigned short* __restrict__ zb) {
  __shared__ float in_lds[192];
  const int j = threadIdx.x;
  float w[192];
#pragma unroll
  for (int k = 0; k < 192; ++k) w[k] = W1[k * 64 + j];
  const float bj = b1[j], gj = g1[j], bej = be1[j];
  for (int n = blockIdx.x; n < N_NODES; n += gridDim.x) {
    in_lds[j] = h0[(size_t)n * 128 + j];
    in_lds[64 + j] = h0[(size_t)n * 128 + 64 + j];
    in_lds[128 + j] = agg[(size_t)n * 64 + j];
    __syncthreads();
    float sum = bj;
#pragma unroll
    for (int k = 0; k < 192; ++k) sum += in_lds[k] * w[k];
    const float h = fmaxf(sum, 0.0f);
    float s1 = h, s2 = h * h;
#pragma unroll
    for (int o = 32; o; o >>= 1) { s1 += __shfl_xor(s1, o); s2 += __shfl_xor(s2, o); }
    const float m = s1 * (1.0f / 64.0f);
    const float var = s2 * (1.0f / 64.0f) - m * m;
    zb[(size_t)n * 64 + j] = f2bf((h - m) * rsqrtf(var + EPS) * gj + bej);
    __syncthreads();
  }
}

// ---------------- edge classifier via MFMA ----------------
__global__ void __launch_bounds__(256) k_cls_mfma(
    const unsigned short* __restrict__ zb, const int* __restrict__ ei,
    const float* __restrict__ Wc0, const float* __restrict__ bc0,
    const float* __restrict__ Wc1, const float* __restrict__ bc1,
    float* __restrict__ out) {
  __shared__ unsigned short atile[64 * 128];  // 16 KB
  const int t = threadIdx.x;
  const int lane = t & 63;
  const int w = t >> 6;     // wave 0..3 -> edge rows [w*16, w*16+16)
  const int m = lane & 15;
  const int g = lane >> 4;  // 0..3

  short8 bfrag[4][4];
#pragma unroll
  for (int ks = 0; ks < 4; ++ks)
#pragma unroll
    for (int nt = 0; nt < 4; ++nt) {
      short8 f;
#pragma unroll
      for (int j = 0; j < 8; ++j)
        f[j] = (short)f2bf(Wc0[(ks * 32 + 8 * g + j) * 64 + nt * 16 + m]);
      bfrag[ks][nt] = f;
    }
  float wc1v0[4], wc1v1[4], bc0v[4];
#pragma unroll
  for (int nt = 0; nt < 4; ++nt) {
    const int j = nt * 16 + m;
    wc1v0[nt] = Wc1[j * 2 + 0];
    wc1v1[nt] = Wc1[j * 2 + 1];
    bc0v[nt] = bc0[j];
  }
  const float ob0 = bc1[0], ob1 = bc1[1];

  for (int tile = blockIdx.x; tile < N_EDGES / 64; tile += gridDim.x) {
    const int ebase = tile * 64;
#pragma unroll
    for (int ro = 0; ro < 4; ++ro) {
      const int hr = ro * 32 + (t >> 3);
      const int el = hr >> 1, half = hr & 1;
      const int e = ebase + el;
      const int node = half ? ei[N_EDGES + e] : ei[e];
      const uint4 v = *(const uint4*)(zb + (size_t)node * 64 + (t & 7) * 8);
      const int col = (half * 128 + (t & 7) * 16) ^ ((el & 7) << 4);
      *(uint4*)((char*)atile + el * 256 + col) = v;
    }
    __syncthreads();

    f32x4 acc0 = {0.f, 0.f, 0.f, 0.f}, acc1 = acc0, acc2 = acc0, acc3 = acc0;
#pragma unroll
    for (int ks = 0; ks < 4; ++ks) {
      const int row = w * 16 + m;
      const int col = (ks * 64 + g * 16) ^ ((row & 7) << 4);
      const short8 a = *(const short8*)((const char*)atile + row * 256 + col);
      acc0 = __builtin_amdgcn_mfma_f32_16x16x32_bf16(a, bfrag[ks][0], acc0, 0, 0, 0);
      acc1 = __builtin_amdgcn_mfma_f32_16x16x32_bf16(a, bfrag[ks][1], acc1, 0, 0, 0);
      acc2 = __builtin_amdgcn_mfma_f32_16x16x32_bf16(a, bfrag[ks][2], acc2, 0, 0, 0);
      acc3 = __builtin_amdgcn_mfma_f32_16x16x32_bf16(a, bfrag[ks][3], acc3, 0, 0, 0);
    }
    float p0[4], p1[4];
#pragma unroll
    for (int r = 0; r < 4; ++r) { p0[r] = 0.f; p1[r] = 0.f; }
#pragma unroll
    for (int r = 0; r < 4; ++r) {
      const float h0v = fmaxf(acc0[r] + bc0v[0], 0.f);
      const float h1v = fmaxf(acc1[r] + bc0v[1], 0.f);
      const float h2v = fmaxf(acc2[r] + bc0v[2], 0.f);
      const float h3v = fmaxf(acc3[r] + bc0v[3], 0.f);
      p0[r] = h0v * wc1v0[0] + h1v * wc1v0[1] + h2v * wc1v0[2] + h3v * wc1v0[3];
      p1[r] = h0v * wc1v1[0] + h1v * wc1v1[1] + h2v * wc1v1[2] + h3v * wc1v1[3];
    }
#pragma unroll
    for (int mask = 1; mask <= 8; mask <<= 1)
#pragma unroll
      for (int r = 0; r < 4; ++r) {
        p0[r] += __shfl_xor(p0[r], mask);
        p1[r] += __shfl_xor(p1[r], mask);
      }
    const int eout = ebase + w * 16 + g * 4;
#pragma unroll
    for (int r = 0; r < 4; ++r) {
      if (m == 2 * r) out[(size_t)(eout + r) * 2 + 0] = p0[r] + ob0;
      if (m == 2 * r + 1) out[(size_t)(eout + r) * 2 + 1] = p1[r] + ob1;
    }
    __syncthreads();
  }
}

extern "C" void kernel_launch(void* const* d_in, const int* in_sizes, int n_in,
                              void* d_out, int out_size, void* d_ws, size_t ws_size,
                              hipStream_t stream) {
  const float* x   = (const float*)d_in[0];
  const int*   ei  = (const int*)d_in[1];
  const float* ea  = (const float*)d_in[2];
  const float* W0  = (const float*)d_in[3];
  const float* b0  = (const float*)d_in[4];
  const float* g0  = (const float*)d_in[5];
  const float* be0 = (const float*)d_in[6];
  const float* W1  = (const float*)d_in[7];
  const float* b1  = (const float*)d_in[8];
  const float* g1  = (const float*)d_in[9];
  const float* be1 = (const float*)d_in[10];
  const float* Wc0 = (const float*)d_in[11];
  const float* bc0 = (const float*)d_in[12];
  const float* Wc1 = (const float*)d_in[13];
  const float* bc1 = (const float*)d_in[14];
  float* out = (float*)d_out;

  float* ws  = (float*)d_ws;
  float* agg = ws;                                     // N*64 f32
  float* h0  = agg + (size_t)N_NODES * 64;             // N*128 f32 (csr aliases)
  unsigned short* zb = (unsigned short*)(h0 + (size_t)N_NODES * 128);  // N*64 bf16
  int* cnt    = (int*)(zb + (size_t)N_NODES * 64);     // N
  int* starts = cnt + N_NODES;                         // N+1 (+3 pad)
  int* pos    = starts + N_NODES + 4;                  // N (16B-aligned)
  int* bsum   = pos + N_NODES;                         // SCAN_BLOCKS
  int* csr    = (int*)h0;                              // E ints, dead before h0 written

  hipMemsetAsync(cnt, 0, N_NODES * sizeof(int), stream);
  k_count<<<(N_EDGES + 255) / 256, 256, 0, stream>>>(ei, cnt);
  k_scan_blk<<<SCAN_BLOCKS, 256, 0, stream>>>(cnt, starts, bsum);
  k_scan_top<<<1, 64, 0, stream>>>(bsum);
  k_scan_add<<<SCAN_BLOCKS, 256, 0, stream>>>(starts, pos, bsum);
  k_place<<<(N_EDGES + 255) / 256, 256, 0, stream>>>(ei, pos, csr);
  k_gather<<<12500, 256, 0, stream>>>(ea, csr, starts, agg);
  k_layer0<<<1024, 128, 0, stream>>>(x, agg, W0, b0, g0, be0, h0);
  k_layer1<<<2048, 64, 0, stream>>>(h0, agg, W1, b1, g1, be1, zb);
  k_cls_mfma<<<2048, 256, 0, stream>>>(zb, ei, Wc0, bc0, Wc1, bc1, out);
}

// Round 6
// 226.769 us; speedup vs baseline: 5.7932x; 1.5622x over previous
//
#include <hip/hip_runtime.h>
#include <hip/hip_bf16.h>

#define N_NODES 50000
#define N_EDGES 800000
#define EPS 1e-5f
#define SCAN_BLOCKS 49  // 49 * 1024 = 50176 >= N_NODES

typedef __attribute__((ext_vector_type(8))) short short8;
typedef __attribute__((ext_vector_type(4))) float f32x4;

static __device__ __forceinline__ unsigned short f2bf(float f) {
  union { float f; unsigned u; } v; v.f = f;
  const unsigned r = v.u + 0x7FFF + ((v.u >> 16) & 1);  // RNE
  return (unsigned short)(r >> 16);
}

// ---------------- weight prep: transpose + bf16 ----------------
// W0T[n][k] (128x128), W1T[n][k] (64x192), Wc0T[n][k] (64x128)
__global__ void __launch_bounds__(256) k_prepw(
    const float* __restrict__ W0, const float* __restrict__ W1,
    const float* __restrict__ Wc0,
    unsigned short* __restrict__ W0T, unsigned short* __restrict__ W1T,
    unsigned short* __restrict__ Wc0T) {
  const int idx = blockIdx.x * 256 + threadIdx.x;
  if (idx < 128 * 128) {
    const int n = idx >> 7, k = idx & 127;
    W0T[idx] = f2bf(W0[k * 128 + n]);
  }
  if (idx < 64 * 192) {
    const int n = idx / 192, k = idx - n * 192;
    W1T[idx] = f2bf(W1[k * 64 + n]);
  }
  if (idx < 64 * 128) {
    const int n = idx >> 7, k = idx & 127;
    Wc0T[idx] = f2bf(Wc0[k * 64 + n]);
  }
}

// ---------------- zero cnt ----------------
__global__ void __launch_bounds__(256) k_zero(int* __restrict__ cnt) {
  const int base = blockIdx.x * 1024 + threadIdx.x * 4;
  if (base + 3 < N_NODES) {
    *(int4*)(cnt + base) = make_int4(0, 0, 0, 0);
  } else {
    for (int i = 0; i < 4; ++i)
      if (base + i < N_NODES) cnt[base + i] = 0;
  }
}

// ---------------- CSR build: count, scan(3-phase), place ----------------
__global__ void k_count(const int* __restrict__ ei, int* __restrict__ cnt) {
  const int e = blockIdx.x * blockDim.x + threadIdx.x;
  if (e < N_EDGES) atomicAdd(&cnt[ei[N_EDGES + e]], 1);
}

__global__ void __launch_bounds__(256) k_scan_blk(const int* __restrict__ cnt,
                                                  int* __restrict__ starts,
                                                  int* __restrict__ bsum) {
  __shared__ int lds[256];
  const int t = threadIdx.x, b = blockIdx.x;
  const int base = b * 1024 + t * 4;
  int c0 = 0, c1 = 0, c2 = 0, c3 = 0;
  if (base + 3 < N_NODES) {
    const int4 c = *(const int4*)(cnt + base);
    c0 = c.x; c1 = c.y; c2 = c.z; c3 = c.w;
  } else {
    if (base + 0 < N_NODES) c0 = cnt[base + 0];
    if (base + 1 < N_NODES) c1 = cnt[base + 1];
    if (base + 2 < N_NODES) c2 = cnt[base + 2];
    if (base + 3 < N_NODES) c3 = cnt[base + 3];
  }
  const int s = c0 + c1 + c2 + c3;
  lds[t] = s;
  __syncthreads();
  for (int off = 1; off < 256; off <<= 1) {
    const int v = (t >= off) ? lds[t - off] : 0;
    __syncthreads();
    lds[t] += v;
    __syncthreads();
  }
  int run = lds[t] - s;
  if (t == 255) bsum[b] = lds[255];
  const int o0 = run; run += c0;
  const int o1 = run; run += c1;
  const int o2 = run; run += c2;
  const int o3 = run;
  if (base + 3 < N_NODES) {
    *(int4*)(starts + base) = make_int4(o0, o1, o2, o3);
  } else {
    if (base + 0 < N_NODES) starts[base + 0] = o0;
    if (base + 1 < N_NODES) starts[base + 1] = o1;
    if (base + 2 < N_NODES) starts[base + 2] = o2;
    if (base + 3 < N_NODES) starts[base + 3] = o3;
  }
}

__global__ void __launch_bounds__(64) k_scan_top(int* __restrict__ bsum) {
  const int t = threadIdx.x;
  int v = (t < SCAN_BLOCKS) ? bsum[t] : 0;
  const int orig = v;
  for (int off = 1; off < 64; off <<= 1) {
    const int u = __shfl_up(v, off);
    if (t >= off) v += u;
  }
  if (t < SCAN_BLOCKS) bsum[t] = v - orig;
}

__global__ void __launch_bounds__(256) k_scan_add(int* __restrict__ starts,
                                                  int* __restrict__ pos,
                                                  const int* __restrict__ bsum) {
  const int t = threadIdx.x, b = blockIdx.x;
  const int off = bsum[b];
  const int base = b * 1024 + t * 4;
  if (base + 3 < N_NODES) {
    int4 v = *(const int4*)(starts + base);
    v.x += off; v.y += off; v.z += off; v.w += off;
    *(int4*)(starts + base) = v;
    *(int4*)(pos + base) = v;
  } else {
    for (int i = 0; i < 4; ++i)
      if (base + i < N_NODES) {
        const int v = starts[base + i] + off;
        starts[base + i] = v;
        pos[base + i] = v;
      }
  }
  if (b == 0 && t == 0) starts[N_NODES] = N_EDGES;
}

__global__ void k_place(const int* __restrict__ ei, int* __restrict__ pos,
                        int* __restrict__ csr) {
  const int e = blockIdx.x * blockDim.x + threadIdx.x;
  if (e < N_EDGES) {
    const int d = ei[N_EDGES + e];
    const int slot = atomicAdd(&pos[d], 1);
    csr[slot] = e;
  }
}

// ---------------- gather-mean -> agg bf16 ----------------
__global__ void __launch_bounds__(256) k_gather(const float* __restrict__ ea,
                                                const int* __restrict__ csr,
                                                const int* __restrict__ starts,
                                                unsigned short* __restrict__ aggb) {
  const int lane = threadIdx.x & 63;
  const int wv = threadIdx.x >> 6;
  const int wstride = gridDim.x * 4;
  for (int n = blockIdx.x * 4 + wv; n < N_NODES; n += wstride) {
    const int s0 = starts[n], s1 = starts[n + 1];
    float sum = 0.0f;
    int i = s0;
    for (; i + 3 < s1; i += 4) {
      const int e0 = csr[i], e1 = csr[i + 1], e2 = csr[i + 2], e3 = csr[i + 3];
      const float a0 = ea[(size_t)e0 * 64 + lane];
      const float a1 = ea[(size_t)e1 * 64 + lane];
      const float a2 = ea[(size_t)e2 * 64 + lane];
      const float a3 = ea[(size_t)e3 * 64 + lane];
      sum += (a0 + a1) + (a2 + a3);
    }
    for (; i < s1; ++i) sum += ea[(size_t)csr[i] * 64 + lane];
    const int deg = s1 - s0;
    aggb[(size_t)n * 64 + lane] = f2bf(sum / (float)max(deg, 1));
  }
}

// ---------------- fused node MLP: L0 -> LN -> L1 -> LN -> zb (bf16) ----------------
// 64-node tile per block, 256 threads (4 waves). MFMA 16x16x32 bf16.
__global__ void __launch_bounds__(256) k_nodes(
    const float* __restrict__ x, const unsigned short* __restrict__ aggb,
    const unsigned short* __restrict__ W0T, const float* __restrict__ b0,
    const float* __restrict__ g0, const float* __restrict__ be0,
    const unsigned short* __restrict__ W1T, const float* __restrict__ b1,
    const float* __restrict__ g1, const float* __restrict__ be1,
    unsigned short* __restrict__ zb) {
  __shared__ char A0[64 * 256];   // [64][128] bf16, 256B rows, XOR-swizzled
  __shared__ char A1[64 * 384];   // [64][192] bf16, 384B rows, XOR-swizzled
  __shared__ float red0[64][4], red1[64][4];

  const int t = threadIdx.x;
  const int lane = t & 63;
  const int w = t >> 6;       // wave id: output-col group
  const int m = lane & 15;
  const int g = lane >> 4;
  const int nbase = blockIdx.x * 64;

  // ---- stage A0 = [x | agg] bf16, swizzled ----
  {
    const int row = t >> 2, seg = t & 3;  // 4 threads per row, 16 cols each
    const int node = nbase + row;
    const int swz = (row & 7) << 4;
    unsigned short h[16];
    if (node < N_NODES) {
      const float4* xr = (const float4*)(x + (size_t)node * 64 + seg * 16);
#pragma unroll
      for (int i = 0; i < 4; ++i) {
        const float4 v = xr[i];
        h[4 * i + 0] = f2bf(v.x); h[4 * i + 1] = f2bf(v.y);
        h[4 * i + 2] = f2bf(v.z); h[4 * i + 3] = f2bf(v.w);
      }
    } else {
#pragma unroll
      for (int i = 0; i < 16; ++i) h[i] = 0;
    }
    uint4 lo, hi;
    unsigned* lp = (unsigned*)&lo;
    unsigned* hp = (unsigned*)&hi;
#pragma unroll
    for (int i = 0; i < 4; ++i) lp[i] = (unsigned)h[2 * i] | ((unsigned)h[2 * i + 1] << 16);
#pragma unroll
    for (int i = 0; i < 4; ++i) hp[i] = (unsigned)h[8 + 2 * i] | ((unsigned)h[8 + 2 * i + 1] << 16);
    *(uint4*)(A0 + row * 256 + ((seg * 32) ^ swz)) = lo;
    *(uint4*)(A0 + row * 256 + ((seg * 32 + 16) ^ swz)) = hi;
    // agg half (bf16, direct copy)
    uint4 a0v = make_uint4(0, 0, 0, 0), a1v = make_uint4(0, 0, 0, 0);
    if (node < N_NODES) {
      const uint4* ap = (const uint4*)(aggb + (size_t)node * 64 + seg * 16);
      a0v = ap[0]; a1v = ap[1];
    }
    *(uint4*)(A0 + row * 256 + ((128 + seg * 32) ^ swz)) = a0v;
    *(uint4*)(A0 + row * 256 + ((128 + seg * 32 + 16) ^ swz)) = a1v;
    // A1 agg region (cols 128..191): bytes 256..383
    *(uint4*)(A1 + row * 384 + ((256 + seg * 32) ^ swz)) = a0v;
    *(uint4*)(A1 + row * 384 + ((256 + seg * 32 + 16) ^ swz)) = a1v;
  }

  // B0 frags: wave w -> cols [32w, 32w+32); K = 128 -> 4 K-blocks of 32
  short8 B0[4][2];
#pragma unroll
  for (int ks = 0; ks < 4; ++ks)
#pragma unroll
    for (int nt = 0; nt < 2; ++nt) {
      const int n = w * 32 + nt * 16 + m;
      B0[ks][nt] = *(const short8*)(W0T + n * 128 + ks * 32 + 8 * g);
    }

  __syncthreads();

  // ---- L0 MFMA: [64x128] @ [128x32] per wave ----
  f32x4 acc0[4][2];
#pragma unroll
  for (int mt = 0; mt < 4; ++mt)
#pragma unroll
    for (int nt = 0; nt < 2; ++nt) acc0[mt][nt] = (f32x4){0.f, 0.f, 0.f, 0.f};
#pragma unroll
  for (int ks = 0; ks < 4; ++ks)
#pragma unroll
    for (int mt = 0; mt < 4; ++mt) {
      const int row = 16 * mt + m;
      const short8 a = *(const short8*)(A0 + row * 256 + ((ks * 64 + g * 16) ^ ((row & 7) << 4)));
      acc0[mt][0] = __builtin_amdgcn_mfma_f32_16x16x32_bf16(a, B0[ks][0], acc0[mt][0], 0, 0, 0);
      acc0[mt][1] = __builtin_amdgcn_mfma_f32_16x16x32_bf16(a, B0[ks][1], acc0[mt][1], 0, 0, 0);
    }

  // ---- LN0 part 1: per-row partial sums over this wave's 32 cols ----
  float b0c[2], g0c[2], be0c[2];
#pragma unroll
  for (int nt = 0; nt < 2; ++nt) {
    const int c = w * 32 + nt * 16 + m;
    b0c[nt] = b0[c]; g0c[nt] = g0[c]; be0c[nt] = be0[c];
  }
  float ps1[4][4], ps2[4][4];
#pragma unroll
  for (int mt = 0; mt < 4; ++mt)
#pragma unroll
    for (int q = 0; q < 4; ++q) {
      const float v0 = fmaxf(acc0[mt][0][q] + b0c[0], 0.f);
      const float v1 = fmaxf(acc0[mt][1][q] + b0c[1], 0.f);
      ps1[mt][q] = v0 + v1;
      ps2[mt][q] = v0 * v0 + v1 * v1;
    }
#pragma unroll
  for (int mask = 1; mask <= 8; mask <<= 1)
#pragma unroll
    for (int mt = 0; mt < 4; ++mt)
#pragma unroll
      for (int q = 0; q < 4; ++q) {
        ps1[mt][q] += __shfl_xor(ps1[mt][q], mask);
        ps2[mt][q] += __shfl_xor(ps2[mt][q], mask);
      }
  if (m == 0) {
#pragma unroll
    for (int mt = 0; mt < 4; ++mt)
#pragma unroll
      for (int q = 0; q < 4; ++q) {
        const int row = 16 * mt + 4 * g + q;
        red0[row][w] = ps1[mt][q];
        red1[row][w] = ps2[mt][q];
      }
  }
  __syncthreads();

  // ---- LN0 part 2: normalize, write h0' (bf16) into A1 cols 0..127 ----
#pragma unroll
  for (int mt = 0; mt < 4; ++mt)
#pragma unroll
    for (int q = 0; q < 4; ++q) {
      const int row = 16 * mt + 4 * g + q;
      const float4 r0 = *(const float4*)red0[row];
      const float4 r1 = *(const float4*)red1[row];
      const float S1 = (r0.x + r0.y) + (r0.z + r0.w);
      const float S2 = (r1.x + r1.y) + (r1.z + r1.w);
      const float mean = S1 * (1.0f / 128.0f);
      const float var = S2 * (1.0f / 128.0f) - mean * mean;
      const float inv = rsqrtf(var + EPS);
#pragma unroll
      for (int nt = 0; nt < 2; ++nt) {
        const float v = fmaxf(acc0[mt][nt][q] + b0c[nt], 0.f);
        const float o = (v - mean) * inv * g0c[nt] + be0c[nt];
        const int col = w * 32 + nt * 16 + m;
        *(unsigned short*)(A1 + row * 384 + ((2 * col) ^ ((row & 7) << 4))) = f2bf(o);
      }
    }

  // B1 frags: wave w -> cols [16w, 16w+16); K = 192 -> 6 K-blocks of 32
  short8 B1[6];
  {
    const int n = w * 16 + m;
#pragma unroll
    for (int ks = 0; ks < 6; ++ks)
      B1[ks] = *(const short8*)(W1T + n * 192 + ks * 32 + 8 * g);
  }
  __syncthreads();

  // ---- L1 MFMA: [64x192] @ [192x16] per wave ----
  f32x4 acc1[4];
#pragma unroll
  for (int mt = 0; mt < 4; ++mt) acc1[mt] = (f32x4){0.f, 0.f, 0.f, 0.f};
#pragma unroll
  for (int ks = 0; ks < 6; ++ks)
#pragma unroll
    for (int mt = 0; mt < 4; ++mt) {
      const int row = 16 * mt + m;
      const short8 a = *(const short8*)(A1 + row * 384 + ((ks * 64 + g * 16) ^ ((row & 7) << 4)));
      acc1[mt] = __builtin_amdgcn_mfma_f32_16x16x32_bf16(a, B1[ks], acc1[mt], 0, 0, 0);
    }

  // ---- LN1 over 64 cols ----
  const int c1i = w * 16 + m;
  const float b1c = b1[c1i], g1c = g1[c1i], be1c = be1[c1i];
  float qs1[4][4], qs2[4][4];
#pragma unroll
  for (int mt = 0; mt < 4; ++mt)
#pragma unroll
    for (int q = 0; q < 4; ++q) {
      const float v = fmaxf(acc1[mt][q] + b1c, 0.f);
      qs1[mt][q] = v;
      qs2[mt][q] = v * v;
    }
#pragma unroll
  for (int mask = 1; mask <= 8; mask <<= 1)
#pragma unroll
    for (int mt = 0; mt < 4; ++mt)
#pragma unroll
      for (int q = 0; q < 4; ++q) {
        qs1[mt][q] += __shfl_xor(qs1[mt][q], mask);
        qs2[mt][q] += __shfl_xor(qs2[mt][q], mask);
      }
  if (m == 0) {
#pragma unroll
    for (int mt = 0; mt < 4; ++mt)
#pragma unroll
      for (int q = 0; q < 4; ++q) {
        const int row = 16 * mt + 4 * g + q;
        red0[row][w] = qs1[mt][q];
        red1[row][w] = qs2[mt][q];
      }
  }
  __syncthreads();
#pragma unroll
  for (int mt = 0; mt < 4; ++mt)
#pragma unroll
    for (int q = 0; q < 4; ++q) {
      const int row = 16 * mt + 4 * g + q;
      const int node = nbase + row;
      const float4 r0 = *(const float4*)red0[row];
      const float4 r1 = *(const float4*)red1[row];
      const float S1 = (r0.x + r0.y) + (r0.z + r0.w);
      const float S2 = (r1.x + r1.y) + (r1.z + r1.w);
      const float mean = S1 * (1.0f / 64.0f);
      const float var = S2 * (1.0f / 64.0f) - mean * mean;
      const float inv = rsqrtf(var + EPS);
      const float v = fmaxf(acc1[mt][q] + b1c, 0.f);
      const float o = (v - mean) * inv * g1c + be1c;
      if (node < N_NODES) zb[(size_t)node * 64 + c1i] = f2bf(o);
    }
}

// ---------------- edge classifier via MFMA ----------------
__global__ void __launch_bounds__(256) k_cls_mfma(
    const unsigned short* __restrict__ zb, const int* __restrict__ ei,
    const unsigned short* __restrict__ Wc0T, const float* __restrict__ bc0,
    const float* __restrict__ Wc1, const float* __restrict__ bc1,
    float* __restrict__ out) {
  __shared__ unsigned short atile[64 * 128];  // 16 KB
  const int t = threadIdx.x;
  const int lane = t & 63;
  const int w = t >> 6;
  const int m = lane & 15;
  const int g = lane >> 4;

  short8 bfrag[4][4];
#pragma unroll
  for (int ks = 0; ks < 4; ++ks)
#pragma unroll
    for (int nt = 0; nt < 4; ++nt)
      bfrag[ks][nt] = *(const short8*)(Wc0T + (nt * 16 + m) * 128 + ks * 32 + 8 * g);
  float wc1v0[4], wc1v1[4], bc0v[4];
#pragma unroll
  for (int nt = 0; nt < 4; ++nt) {
    const int j = nt * 16 + m;
    wc1v0[nt] = Wc1[j * 2 + 0];
    wc1v1[nt] = Wc1[j * 2 + 1];
    bc0v[nt] = bc0[j];
  }
  const float ob0 = bc1[0], ob1 = bc1[1];

  for (int tile = blockIdx.x; tile < N_EDGES / 64; tile += gridDim.x) {
    const int ebase = tile * 64;
#pragma unroll
    for (int ro = 0; ro < 4; ++ro) {
      const int hr = ro * 32 + (t >> 3);
      const int el = hr >> 1, half = hr & 1;
      const int e = ebase + el;
      const int node = half ? ei[N_EDGES + e] : ei[e];
      const uint4 v = *(const uint4*)(zb + (size_t)node * 64 + (t & 7) * 8);
      const int col = (half * 128 + (t & 7) * 16) ^ ((el & 7) << 4);
      *(uint4*)((char*)atile + el * 256 + col) = v;
    }
    __syncthreads();

    f32x4 acc0 = {0.f, 0.f, 0.f, 0.f}, acc1 = acc0, acc2 = acc0, acc3 = acc0;
#pragma unroll
    for (int ks = 0; ks < 4; ++ks) {
      const int row = w * 16 + m;
      const int col = (ks * 64 + g * 16) ^ ((row & 7) << 4);
      const short8 a = *(const short8*)((const char*)atile + row * 256 + col);
      acc0 = __builtin_amdgcn_mfma_f32_16x16x32_bf16(a, bfrag[ks][0], acc0, 0, 0, 0);
      acc1 = __builtin_amdgcn_mfma_f32_16x16x32_bf16(a, bfrag[ks][1], acc1, 0, 0, 0);
      acc2 = __builtin_amdgcn_mfma_f32_16x16x32_bf16(a, bfrag[ks][2], acc2, 0, 0, 0);
      acc3 = __builtin_amdgcn_mfma_f32_16x16x32_bf16(a, bfrag[ks][3], acc3, 0, 0, 0);
    }
    float p0[4], p1[4];
#pragma unroll
    for (int r = 0; r < 4; ++r) {
      const float h0v = fmaxf(acc0[r] + bc0v[0], 0.f);
      const float h1v = fmaxf(acc1[r] + bc0v[1], 0.f);
      const float h2v = fmaxf(acc2[r] + bc0v[2], 0.f);
      const float h3v = fmaxf(acc3[r] + bc0v[3], 0.f);
      p0[r] = h0v * wc1v0[0] + h1v * wc1v0[1] + h2v * wc1v0[2] + h3v * wc1v0[3];
      p1[r] = h0v * wc1v1[0] + h1v * wc1v1[1] + h2v * wc1v1[2] + h3v * wc1v1[3];
    }
#pragma unroll
    for (int mask = 1; mask <= 8; mask <<= 1)
#pragma unroll
      for (int r = 0; r < 4; ++r) {
        p0[r] += __shfl_xor(p0[r], mask);
        p1[r] += __shfl_xor(p1[r], mask);
      }
    const int eout = ebase + w * 16 + g * 4;
#pragma unroll
    for (int r = 0; r < 4; ++r) {
      if (m == 2 * r) out[(size_t)(eout + r) * 2 + 0] = p0[r] + ob0;
      if (m == 2 * r + 1) out[(size_t)(eout + r) * 2 + 1] = p1[r] + ob1;
    }
    __syncthreads();
  }
}

extern "C" void kernel_launch(void* const* d_in, const int* in_sizes, int n_in,
                              void* d_out, int out_size, void* d_ws, size_t ws_size,
                              hipStream_t stream) {
  const float* x   = (const float*)d_in[0];
  const int*   ei  = (const int*)d_in[1];
  const float* ea  = (const float*)d_in[2];
  const float* W0  = (const float*)d_in[3];
  const float* b0  = (const float*)d_in[4];
  const float* g0  = (const float*)d_in[5];
  const float* be0 = (const float*)d_in[6];
  const float* W1  = (const float*)d_in[7];
  const float* b1  = (const float*)d_in[8];
  const float* g1  = (const float*)d_in[9];
  const float* be1 = (const float*)d_in[10];
  const float* Wc0 = (const float*)d_in[11];
  const float* bc0 = (const float*)d_in[12];
  const float* Wc1 = (const float*)d_in[13];
  const float* bc1 = (const float*)d_in[14];
  float* out = (float*)d_out;

  char* base = (char*)d_ws;
  unsigned short* zb   = (unsigned short*)base;                       // N*64 bf16
  unsigned short* aggb = zb + (size_t)N_NODES * 64;                   // N*64 bf16
  unsigned short* W0T  = aggb + (size_t)N_NODES * 64;                 // 128*128
  unsigned short* W1T  = W0T + 128 * 128;                             // 64*192
  unsigned short* Wc0T = W1T + 64 * 192;                              // 64*128
  int* cnt    = (int*)(Wc0T + 64 * 128);                              // N
  int* starts = cnt + N_NODES;                                        // N+1 (+pad)
  int* pos    = starts + N_NODES + 4;                                 // N
  int* bsum   = pos + N_NODES;                                        // 64
  int* csr    = bsum + 64;                                            // E

  k_prepw<<<64, 256, 0, stream>>>(W0, W1, Wc0, W0T, W1T, Wc0T);
  k_zero<<<SCAN_BLOCKS, 256, 0, stream>>>(cnt);
  k_count<<<(N_EDGES + 255) / 256, 256, 0, stream>>>(ei, cnt);
  k_scan_blk<<<SCAN_BLOCKS, 256, 0, stream>>>(cnt, starts, bsum);
  k_scan_top<<<1, 64, 0, stream>>>(bsum);
  k_scan_add<<<SCAN_BLOCKS, 256, 0, stream>>>(starts, pos, bsum);
  k_place<<<(N_EDGES + 255) / 256, 256, 0, stream>>>(ei, pos, csr);
  k_gather<<<12500, 256, 0, stream>>>(ea, csr, starts, aggb);
  k_nodes<<<(N_NODES + 63) / 64, 256, 0, stream>>>(x, aggb, W0T, b0, g0, be0,
                                                   W1T, b1, g1, be1, zb);
  k_cls_mfma<<<2048, 256, 0, stream>>>(zb, ei, Wc0T, bc0, Wc1, bc1, out);
}

// Round 7
// 213.802 us; speedup vs baseline: 6.1445x; 1.0606x over previous
//
#include <hip/hip_runtime.h>
#include <hip/hip_bf16.h>

#define N_NODES 50000
#define N_EDGES 800000
#define EPS 1e-5f
#define SCAN_BLOCKS 49  // 49 * 1024 = 50176 >= N_NODES

typedef __attribute__((ext_vector_type(8))) short short8;
typedef __attribute__((ext_vector_type(4))) float f32x4;

static __device__ __forceinline__ unsigned short f2bf(float f) {
  union { float f; unsigned u; } v; v.f = f;
  const unsigned r = v.u + 0x7FFF + ((v.u >> 16) & 1);  // RNE
  return (unsigned short)(r >> 16);
}

// ---------------- weight prep (transpose + bf16) + cnt zero ----------------
__global__ void __launch_bounds__(256) k_prepw(
    const float* __restrict__ W0, const float* __restrict__ W1,
    const float* __restrict__ Wc0,
    unsigned short* __restrict__ W0T, unsigned short* __restrict__ W1T,
    unsigned short* __restrict__ Wc0T, int* __restrict__ cnt) {
  const int idx = blockIdx.x * 256 + threadIdx.x;
  if (idx < 128 * 128) {
    const int n = idx >> 7, k = idx & 127;
    W0T[idx] = f2bf(W0[k * 128 + n]);
  }
  if (idx < 64 * 192) {
    const int n = idx / 192, k = idx - n * 192;
    W1T[idx] = f2bf(W1[k * 64 + n]);
  }
  if (idx < 64 * 128) {
    const int n = idx >> 7, k = idx & 127;
    Wc0T[idx] = f2bf(Wc0[k * 64 + n]);
  }
  for (int i = idx; i < N_NODES; i += 64 * 256) cnt[i] = 0;
}

// ---------------- CSR build: count, scan(2-phase), place ----------------
__global__ void k_count(const int* __restrict__ ei, int* __restrict__ cnt) {
  const int e = blockIdx.x * blockDim.x + threadIdx.x;
  if (e < N_EDGES) atomicAdd(&cnt[ei[N_EDGES + e]], 1);
}

__global__ void __launch_bounds__(256) k_scan_blk(const int* __restrict__ cnt,
                                                  int* __restrict__ starts,
                                                  int* __restrict__ bsum) {
  __shared__ int lds[256];
  const int t = threadIdx.x, b = blockIdx.x;
  const int base = b * 1024 + t * 4;
  int c0 = 0, c1 = 0, c2 = 0, c3 = 0;
  if (base + 3 < N_NODES) {
    const int4 c = *(const int4*)(cnt + base);
    c0 = c.x; c1 = c.y; c2 = c.z; c3 = c.w;
  } else {
    if (base + 0 < N_NODES) c0 = cnt[base + 0];
    if (base + 1 < N_NODES) c1 = cnt[base + 1];
    if (base + 2 < N_NODES) c2 = cnt[base + 2];
    if (base + 3 < N_NODES) c3 = cnt[base + 3];
  }
  const int s = c0 + c1 + c2 + c3;
  lds[t] = s;
  __syncthreads();
  for (int off = 1; off < 256; off <<= 1) {
    const int v = (t >= off) ? lds[t - off] : 0;
    __syncthreads();
    lds[t] += v;
    __syncthreads();
  }
  int run = lds[t] - s;
  if (t == 255) bsum[b] = lds[255];  // block total
  const int o0 = run; run += c0;
  const int o1 = run; run += c1;
  const int o2 = run; run += c2;
  const int o3 = run;
  if (base + 3 < N_NODES) {
    *(int4*)(starts + base) = make_int4(o0, o1, o2, o3);
  } else {
    if (base + 0 < N_NODES) starts[base + 0] = o0;
    if (base + 1 < N_NODES) starts[base + 1] = o1;
    if (base + 2 < N_NODES) starts[base + 2] = o2;
    if (base + 3 < N_NODES) starts[base + 3] = o3;
  }
}

// adds sum(bsum[0..b)) computed in-kernel (49 values, one wave-reduce)
__global__ void __launch_bounds__(256) k_scan_add(int* __restrict__ starts,
                                                  int* __restrict__ pos,
                                                  const int* __restrict__ bsum) {
  __shared__ int s_off;
  const int t = threadIdx.x, b = blockIdx.x;
  if (t < 64) {
    int v = (t < b) ? bsum[t] : 0;  // b <= 48 < 64
    for (int o = 32; o; o >>= 1) v += __shfl_xor(v, o);
    if (t == 0) s_off = v;
  }
  __syncthreads();
  const int off = s_off;
  const int base = b * 1024 + t * 4;
  if (base + 3 < N_NODES) {
    int4 v = *(const int4*)(starts + base);
    v.x += off; v.y += off; v.z += off; v.w += off;
    *(int4*)(starts + base) = v;
    *(int4*)(pos + base) = v;
  } else {
    for (int i = 0; i < 4; ++i)
      if (base + i < N_NODES) {
        const int v = starts[base + i] + off;
        starts[base + i] = v;
        pos[base + i] = v;
      }
  }
  if (b == 0 && t == 0) starts[N_NODES] = N_EDGES;
}

__global__ void k_place(const int* __restrict__ ei, int* __restrict__ pos,
                        int* __restrict__ csr) {
  const int e = blockIdx.x * blockDim.x + threadIdx.x;
  if (e < N_EDGES) {
    const int d = ei[N_EDGES + e];
    const int slot = atomicAdd(&pos[d], 1);
    csr[slot] = e;
  }
}

// ---------------- gather-mean -> agg bf16 ----------------
__global__ void __launch_bounds__(256) k_gather(const float* __restrict__ ea,
                                                const int* __restrict__ csr,
                                                const int* __restrict__ starts,
                                                unsigned short* __restrict__ aggb) {
  const int lane = threadIdx.x & 63;
  const int wv = threadIdx.x >> 6;
  const int wstride = gridDim.x * 4;
  for (int n = blockIdx.x * 4 + wv; n < N_NODES; n += wstride) {
    const int s0 = starts[n], s1 = starts[n + 1];
    float sum = 0.0f;
    int i = s0;
    for (; i + 3 < s1; i += 4) {
      const int e0 = csr[i], e1 = csr[i + 1], e2 = csr[i + 2], e3 = csr[i + 3];
      const float a0 = ea[(size_t)e0 * 64 + lane];
      const float a1 = ea[(size_t)e1 * 64 + lane];
      const float a2 = ea[(size_t)e2 * 64 + lane];
      const float a3 = ea[(size_t)e3 * 64 + lane];
      sum += (a0 + a1) + (a2 + a3);
    }
    for (; i < s1; ++i) sum += ea[(size_t)csr[i] * 64 + lane];
    const int deg = s1 - s0;
    aggb[(size_t)n * 64 + lane] = f2bf(sum / (float)max(deg, 1));
  }
}

// ---------------- fused node MLP: L0 -> LN -> L1 -> LN -> zb (bf16) ----------------
__global__ void __launch_bounds__(256) k_nodes(
    const float* __restrict__ x, const unsigned short* __restrict__ aggb,
    const unsigned short* __restrict__ W0T, const float* __restrict__ b0,
    const float* __restrict__ g0, const float* __restrict__ be0,
    const unsigned short* __restrict__ W1T, const float* __restrict__ b1,
    const float* __restrict__ g1, const float* __restrict__ be1,
    unsigned short* __restrict__ zb) {
  __shared__ char A0[64 * 256];   // [64][128] bf16, 256B rows, XOR-swizzled
  __shared__ char A1[64 * 384];   // [64][192] bf16, 384B rows, XOR-swizzled
  __shared__ float red0[64][4], red1[64][4];

  const int t = threadIdx.x;
  const int lane = t & 63;
  const int w = t >> 6;
  const int m = lane & 15;
  const int g = lane >> 4;
  const int nbase = blockIdx.x * 64;

  {
    const int row = t >> 2, seg = t & 3;
    const int node = nbase + row;
    const int swz = (row & 7) << 4;
    unsigned short h[16];
    if (node < N_NODES) {
      const float4* xr = (const float4*)(x + (size_t)node * 64 + seg * 16);
#pragma unroll
      for (int i = 0; i < 4; ++i) {
        const float4 v = xr[i];
        h[4 * i + 0] = f2bf(v.x); h[4 * i + 1] = f2bf(v.y);
        h[4 * i + 2] = f2bf(v.z); h[4 * i + 3] = f2bf(v.w);
      }
    } else {
#pragma unroll
      for (int i = 0; i < 16; ++i) h[i] = 0;
    }
    uint4 lo, hi;
    unsigned* lp = (unsigned*)&lo;
    unsigned* hp = (unsigned*)&hi;
#pragma unroll
    for (int i = 0; i < 4; ++i) lp[i] = (unsigned)h[2 * i] | ((unsigned)h[2 * i + 1] << 16);
#pragma unroll
    for (int i = 0; i < 4; ++i) hp[i] = (unsigned)h[8 + 2 * i] | ((unsigned)h[8 + 2 * i + 1] << 16);
    *(uint4*)(A0 + row * 256 + ((seg * 32) ^ swz)) = lo;
    *(uint4*)(A0 + row * 256 + ((seg * 32 + 16) ^ swz)) = hi;
    uint4 a0v = make_uint4(0, 0, 0, 0), a1v = make_uint4(0, 0, 0, 0);
    if (node < N_NODES) {
      const uint4* ap = (const uint4*)(aggb + (size_t)node * 64 + seg * 16);
      a0v = ap[0]; a1v = ap[1];
    }
    *(uint4*)(A0 + row * 256 + ((128 + seg * 32) ^ swz)) = a0v;
    *(uint4*)(A0 + row * 256 + ((128 + seg * 32 + 16) ^ swz)) = a1v;
    *(uint4*)(A1 + row * 384 + ((256 + seg * 32) ^ swz)) = a0v;
    *(uint4*)(A1 + row * 384 + ((256 + seg * 32 + 16) ^ swz)) = a1v;
  }

  short8 B0[4][2];
#pragma unroll
  for (int ks = 0; ks < 4; ++ks)
#pragma unroll
    for (int nt = 0; nt < 2; ++nt) {
      const int n = w * 32 + nt * 16 + m;
      B0[ks][nt] = *(const short8*)(W0T + n * 128 + ks * 32 + 8 * g);
    }

  __syncthreads();

  f32x4 acc0[4][2];
#pragma unroll
  for (int mt = 0; mt < 4; ++mt)
#pragma unroll
    for (int nt = 0; nt < 2; ++nt) acc0[mt][nt] = (f32x4){0.f, 0.f, 0.f, 0.f};
#pragma unroll
  for (int ks = 0; ks < 4; ++ks)
#pragma unroll
    for (int mt = 0; mt < 4; ++mt) {
      const int row = 16 * mt + m;
      const short8 a = *(const short8*)(A0 + row * 256 + ((ks * 64 + g * 16) ^ ((row & 7) << 4)));
      acc0[mt][0] = __builtin_amdgcn_mfma_f32_16x16x32_bf16(a, B0[ks][0], acc0[mt][0], 0, 0, 0);
      acc0[mt][1] = __builtin_amdgcn_mfma_f32_16x16x32_bf16(a, B0[ks][1], acc0[mt][1], 0, 0, 0);
    }

  float b0c[2], g0c[2], be0c[2];
#pragma unroll
  for (int nt = 0; nt < 2; ++nt) {
    const int c = w * 32 + nt * 16 + m;
    b0c[nt] = b0[c]; g0c[nt] = g0[c]; be0c[nt] = be0[c];
  }
  float ps1[4][4], ps2[4][4];
#pragma unroll
  for (int mt = 0; mt < 4; ++mt)
#pragma unroll
    for (int q = 0; q < 4; ++q) {
      const float v0 = fmaxf(acc0[mt][0][q] + b0c[0], 0.f);
      const float v1 = fmaxf(acc0[mt][1][q] + b0c[1], 0.f);
      ps1[mt][q] = v0 + v1;
      ps2[mt][q] = v0 * v0 + v1 * v1;
    }
#pragma unroll
  for (int mask = 1; mask <= 8; mask <<= 1)
#pragma unroll
    for (int mt = 0; mt < 4; ++mt)
#pragma unroll
      for (int q = 0; q < 4; ++q) {
        ps1[mt][q] += __shfl_xor(ps1[mt][q], mask);
        ps2[mt][q] += __shfl_xor(ps2[mt][q], mask);
      }
  if (m == 0) {
#pragma unroll
    for (int mt = 0; mt < 4; ++mt)
#pragma unroll
      for (int q = 0; q < 4; ++q) {
        const int row = 16 * mt + 4 * g + q;
        red0[row][w] = ps1[mt][q];
        red1[row][w] = ps2[mt][q];
      }
  }
  __syncthreads();

#pragma unroll
  for (int mt = 0; mt < 4; ++mt)
#pragma unroll
    for (int q = 0; q < 4; ++q) {
      const int row = 16 * mt + 4 * g + q;
      const float4 r0 = *(const float4*)red0[row];
      const float4 r1 = *(const float4*)red1[row];
      const float S1 = (r0.x + r0.y) + (r0.z + r0.w);
      const float S2 = (r1.x + r1.y) + (r1.z + r1.w);
      const float mean = S1 * (1.0f / 128.0f);
      const float var = S2 * (1.0f / 128.0f) - mean * mean;
      const float inv = rsqrtf(var + EPS);
#pragma unroll
      for (int nt = 0; nt < 2; ++nt) {
        const float v = fmaxf(acc0[mt][nt][q] + b0c[nt], 0.f);
        const float o = (v - mean) * inv * g0c[nt] + be0c[nt];
        const int col = w * 32 + nt * 16 + m;
        *(unsigned short*)(A1 + row * 384 + ((2 * col) ^ ((row & 7) << 4))) = f2bf(o);
      }
    }

  short8 B1[6];
  {
    const int n = w * 16 + m;
#pragma unroll
    for (int ks = 0; ks < 6; ++ks)
      B1[ks] = *(const short8*)(W1T + n * 192 + ks * 32 + 8 * g);
  }
  __syncthreads();

  f32x4 acc1[4];
#pragma unroll
  for (int mt = 0; mt < 4; ++mt) acc1[mt] = (f32x4){0.f, 0.f, 0.f, 0.f};
#pragma unroll
  for (int ks = 0; ks < 6; ++ks)
#pragma unroll
    for (int mt = 0; mt < 4; ++mt) {
      const int row = 16 * mt + m;
      const short8 a = *(const short8*)(A1 + row * 384 + ((ks * 64 + g * 16) ^ ((row & 7) << 4)));
      acc1[mt] = __builtin_amdgcn_mfma_f32_16x16x32_bf16(a, B1[ks], acc1[mt], 0, 0, 0);
    }

  const int c1i = w * 16 + m;
  const float b1c = b1[c1i], g1c = g1[c1i], be1c = be1[c1i];
  float qs1[4][4], qs2[4][4];
#pragma unroll
  for (int mt = 0; mt < 4; ++mt)
#pragma unroll
    for (int q = 0; q < 4; ++q) {
      const float v = fmaxf(acc1[mt][q] + b1c, 0.f);
      qs1[mt][q] = v;
      qs2[mt][q] = v * v;
    }
#pragma unroll
  for (int mask = 1; mask <= 8; mask <<= 1)
#pragma unroll
    for (int mt = 0; mt < 4; ++mt)
#pragma unroll
      for (int q = 0; q < 4; ++q) {
        qs1[mt][q] += __shfl_xor(qs1[mt][q], mask);
        qs2[mt][q] += __shfl_xor(qs2[mt][q], mask);
      }
  if (m == 0) {
#pragma unroll
    for (int mt = 0; mt < 4; ++mt)
#pragma unroll
      for (int q = 0; q < 4; ++q) {
        const int row = 16 * mt + 4 * g + q;
        red0[row][w] = qs1[mt][q];
        red1[row][w] = qs2[mt][q];
      }
  }
  __syncthreads();
#pragma unroll
  for (int mt = 0; mt < 4; ++mt)
#pragma unroll
    for (int q = 0; q < 4; ++q) {
      const int row = 16 * mt + 4 * g + q;
      const int node = nbase + row;
      const float4 r0 = *(const float4*)red0[row];
      const float4 r1 = *(const float4*)red1[row];
      const float S1 = (r0.x + r0.y) + (r0.z + r0.w);
      const float S2 = (r1.x + r1.y) + (r1.z + r1.w);
      const float mean = S1 * (1.0f / 64.0f);
      const float var = S2 * (1.0f / 64.0f) - mean * mean;
      const float inv = rsqrtf(var + EPS);
      const float v = fmaxf(acc1[mt][q] + b1c, 0.f);
      const float o = (v - mean) * inv * g1c + be1c;
      if (node < N_NODES) zb[(size_t)node * 64 + c1i] = f2bf(o);
    }
}

// ---------------- edge classifier: LDS-free direct-gather MFMA ----------------
// Each wave owns 16 edges; lane (m,g) gathers its A-fragment (4x16B) straight
// from zb. No LDS, no barriers; latency hidden by TLP.
__global__ void __launch_bounds__(256) k_cls_mfma(
    const unsigned short* __restrict__ zb, const int* __restrict__ ei,
    const unsigned short* __restrict__ Wc0T, const float* __restrict__ bc0,
    const float* __restrict__ Wc1, const float* __restrict__ bc1,
    float* __restrict__ out) {
  const int t = threadIdx.x;
  const int lane = t & 63;
  const int w = t >> 6;
  const int m = lane & 15;
  const int g = lane >> 4;

  short8 bfrag[4][4];
#pragma unroll
  for (int ks = 0; ks < 4; ++ks)
#pragma unroll
    for (int nt = 0; nt < 4; ++nt)
      bfrag[ks][nt] = *(const short8*)(Wc0T + (nt * 16 + m) * 128 + ks * 32 + 8 * g);
  float wc1v0[4], wc1v1[4], bc0v[4];
#pragma unroll
  for (int nt = 0; nt < 4; ++nt) {
    const int j = nt * 16 + m;
    wc1v0[nt] = Wc1[j * 2 + 0];
    wc1v1[nt] = Wc1[j * 2 + 1];
    bc0v[nt] = bc0[j];
  }
  const float ob0 = bc1[0], ob1 = bc1[1];

  const int gstride = gridDim.x * 4;
  for (int grp = blockIdx.x * 4 + w; grp < N_EDGES / 16; grp += gstride) {
    const int ebase = grp * 16;
    const int e = ebase + m;
    const int s = ei[e], d = ei[N_EDGES + e];
    // A-fragments: k-block ks -> elements [ks*32+8g, +8) of [z[s]|z[d]] row
    const short8 a0 = *(const short8*)(zb + (size_t)s * 64 + 8 * g);
    const short8 a1 = *(const short8*)(zb + (size_t)s * 64 + 32 + 8 * g);
    const short8 a2 = *(const short8*)(zb + (size_t)d * 64 + 8 * g);
    const short8 a3 = *(const short8*)(zb + (size_t)d * 64 + 32 + 8 * g);

    f32x4 acc0 = {0.f, 0.f, 0.f, 0.f}, acc1 = acc0, acc2 = acc0, acc3 = acc0;
    acc0 = __builtin_amdgcn_mfma_f32_16x16x32_bf16(a0, bfrag[0][0], acc0, 0, 0, 0);
    acc1 = __builtin_amdgcn_mfma_f32_16x16x32_bf16(a0, bfrag[0][1], acc1, 0, 0, 0);
    acc2 = __builtin_amdgcn_mfma_f32_16x16x32_bf16(a0, bfrag[0][2], acc2, 0, 0, 0);
    acc3 = __builtin_amdgcn_mfma_f32_16x16x32_bf16(a0, bfrag[0][3], acc3, 0, 0, 0);
    acc0 = __builtin_amdgcn_mfma_f32_16x16x32_bf16(a1, bfrag[1][0], acc0, 0, 0, 0);
    acc1 = __builtin_amdgcn_mfma_f32_16x16x32_bf16(a1, bfrag[1][1], acc1, 0, 0, 0);
    acc2 = __builtin_amdgcn_mfma_f32_16x16x32_bf16(a1, bfrag[1][2], acc2, 0, 0, 0);
    acc3 = __builtin_amdgcn_mfma_f32_16x16x32_bf16(a1, bfrag[1][3], acc3, 0, 0, 0);
    acc0 = __builtin_amdgcn_mfma_f32_16x16x32_bf16(a2, bfrag[2][0], acc0, 0, 0, 0);
    acc1 = __builtin_amdgcn_mfma_f32_16x16x32_bf16(a2, bfrag[2][1], acc1, 0, 0, 0);
    acc2 = __builtin_amdgcn_mfma_f32_16x16x32_bf16(a2, bfrag[2][2], acc2, 0, 0, 0);
    acc3 = __builtin_amdgcn_mfma_f32_16x16x32_bf16(a2, bfrag[2][3], acc3, 0, 0, 0);
    acc0 = __builtin_amdgcn_mfma_f32_16x16x32_bf16(a3, bfrag[3][0], acc0, 0, 0, 0);
    acc1 = __builtin_amdgcn_mfma_f32_16x16x32_bf16(a3, bfrag[3][1], acc1, 0, 0, 0);
    acc2 = __builtin_amdgcn_mfma_f32_16x16x32_bf16(a3, bfrag[3][2], acc2, 0, 0, 0);
    acc3 = __builtin_amdgcn_mfma_f32_16x16x32_bf16(a3, bfrag[3][3], acc3, 0, 0, 0);

    float p0[4], p1[4];
#pragma unroll
    for (int r = 0; r < 4; ++r) {
      const float h0v = fmaxf(acc0[r] + bc0v[0], 0.f);
      const float h1v = fmaxf(acc1[r] + bc0v[1], 0.f);
      const float h2v = fmaxf(acc2[r] + bc0v[2], 0.f);
      const float h3v = fmaxf(acc3[r] + bc0v[3], 0.f);
      p0[r] = h0v * wc1v0[0] + h1v * wc1v0[1] + h2v * wc1v0[2] + h3v * wc1v0[3];
      p1[r] = h0v * wc1v1[0] + h1v * wc1v1[1] + h2v * wc1v1[2] + h3v * wc1v1[3];
    }
#pragma unroll
    for (int mask = 1; mask <= 8; mask <<= 1)
#pragma unroll
      for (int r = 0; r < 4; ++r) {
        p0[r] += __shfl_xor(p0[r], mask);
        p1[r] += __shfl_xor(p1[r], mask);
      }
    const int eout = ebase + g * 4;
#pragma unroll
    for (int r = 0; r < 4; ++r) {
      if (m == 2 * r) out[(size_t)(eout + r) * 2 + 0] = p0[r] + ob0;
      if (m == 2 * r + 1) out[(size_t)(eout + r) * 2 + 1] = p1[r] + ob1;
    }
  }
}

extern "C" void kernel_launch(void* const* d_in, const int* in_sizes, int n_in,
                              void* d_out, int out_size, void* d_ws, size_t ws_size,
                              hipStream_t stream) {
  const float* x   = (const float*)d_in[0];
  const int*   ei  = (const int*)d_in[1];
  const float* ea  = (const float*)d_in[2];
  const float* W0  = (const float*)d_in[3];
  const float* b0  = (const float*)d_in[4];
  const float* g0  = (const float*)d_in[5];
  const float* be0 = (const float*)d_in[6];
  const float* W1  = (const float*)d_in[7];
  const float* b1  = (const float*)d_in[8];
  const float* g1  = (const float*)d_in[9];
  const float* be1 = (const float*)d_in[10];
  const float* Wc0 = (const float*)d_in[11];
  const float* bc0 = (const float*)d_in[12];
  const float* Wc1 = (const float*)d_in[13];
  const float* bc1 = (const float*)d_in[14];
  float* out = (float*)d_out;

  char* base = (char*)d_ws;
  unsigned short* zb   = (unsigned short*)base;                       // N*64 bf16
  unsigned short* aggb = zb + (size_t)N_NODES * 64;                   // N*64 bf16
  unsigned short* W0T  = aggb + (size_t)N_NODES * 64;                 // 128*128
  unsigned short* W1T  = W0T + 128 * 128;                             // 64*192
  unsigned short* Wc0T = W1T + 64 * 192;                              // 64*128
  int* cnt    = (int*)(Wc0T + 64 * 128);                              // N
  int* starts = cnt + N_NODES;                                        // N+1 (+pad)
  int* pos    = starts + N_NODES + 4;                                 // N
  int* bsum   = pos + N_NODES;                                        // 64
  int* csr    = bsum + 64;                                            // E

  k_prepw<<<64, 256, 0, stream>>>(W0, W1, Wc0, W0T, W1T, Wc0T, cnt);
  k_count<<<(N_EDGES + 255) / 256, 256, 0, stream>>>(ei, cnt);
  k_scan_blk<<<SCAN_BLOCKS, 256, 0, stream>>>(cnt, starts, bsum);
  k_scan_add<<<SCAN_BLOCKS, 256, 0, stream>>>(starts, pos, bsum);
  k_place<<<(N_EDGES + 255) / 256, 256, 0, stream>>>(ei, pos, csr);
  k_gather<<<12500, 256, 0, stream>>>(ea, csr, starts, aggb);
  k_nodes<<<(N_NODES + 63) / 64, 256, 0, stream>>>(x, aggb, W0T, b0, g0, be0,
                                                   W1T, b1, g1, be1, zb);
  k_cls_mfma<<<2048, 256, 0, stream>>>(zb, ei, Wc0T, bc0, Wc1, bc1, out);
}